// Round 1
// baseline (38.959 us; speedup 1.0000x reference)
//
#include <hip/hip_runtime.h>
#include <math.h>

#define NROWS 8192
#define DD 64

// ---------------------------------------------------------------------------
// Kernel 1: per-row score s[r] = dot(h[r], A[:64]); per-block partial max;
//           stage h[0] into h0copy (needed for in-place layer 2).
// grid 2048 x 256 (4 waves/block, 1 row/wave)
// ---------------------------------------------------------------------------
__global__ __launch_bounds__(256) void score_k(
    const float* __restrict__ h, const float* __restrict__ A,
    float* __restrict__ s, float* __restrict__ pmax, float* __restrict__ h0copy)
{
    int row  = (blockIdx.x * blockDim.x + threadIdx.x) >> 6;
    int lane = threadIdx.x & 63;
    int wl   = threadIdx.x >> 6;

    float w  = A[lane];                 // only A[:64] matters (h1 cancels in softmax)
    float hv = h[row * DD + lane];
    float v  = hv * w;
    #pragma unroll
    for (int off = 32; off; off >>= 1) v += __shfl_xor(v, off);

    if (lane == 0) s[row] = v;
    if (row == 0)  h0copy[lane] = hv;

    __shared__ float sm[4];
    if (lane == 0) sm[wl] = v;
    __syncthreads();
    if (threadIdx.x == 0)
        pmax[blockIdx.x] = fmaxf(fmaxf(sm[0], sm[1]), fmaxf(sm[2], sm[3]));
}

// ---------------------------------------------------------------------------
// Kernel 2: row-0 softmax partials. Each of 64 blocks redundantly reduces
// pmax -> global M, then accumulates partial weighted column-sums and partial
// sum-of-exp over its 128-row chunk. Fixed-order -> deterministic.
// grid 64 x 256
// ---------------------------------------------------------------------------
__global__ __launch_bounds__(256) void row0_partial_k(
    const float* __restrict__ h, const float* __restrict__ s,
    const float* __restrict__ pmax, float* __restrict__ partials,
    float* __restrict__ zpart)
{
    int lane = threadIdx.x & 63;
    int wl   = threadIdx.x >> 6;

    // global max (redundant per block)
    float m = -1e30f;
    for (int i = threadIdx.x; i < 2048; i += 256) m = fmaxf(m, pmax[i]);
    #pragma unroll
    for (int off = 32; off; off >>= 1) m = fmaxf(m, __shfl_xor(m, off));
    __shared__ float wm[4];
    if (lane == 0) wm[wl] = m;
    __syncthreads();
    float M = fmaxf(fmaxf(wm[0], wm[1]), fmaxf(wm[2], wm[3]));

    // chunk of 128 rows, wave-per-row strided by 4
    int r0 = blockIdx.x * 128;
    float acc = 0.f, z = 0.f;
    for (int r = r0 + wl; r < r0 + 128; r += 4) {
        float e = expf(s[r] - M);
        acc += e * h[r * DD + lane];
        z   += e;
    }

    __shared__ float pacc[4][64];
    __shared__ float pz[4];
    pacc[wl][lane] = acc;
    if (lane == 0) pz[wl] = z;
    __syncthreads();
    if (wl == 0) {
        partials[blockIdx.x * DD + lane] =
            pacc[0][lane] + pacc[1][lane] + pacc[2][lane] + pacc[3][lane];
        if (lane == 0) zpart[blockIdx.x] = pz[0] + pz[1] + pz[2] + pz[3];
    }
}

// ---------------------------------------------------------------------------
// Kernel 3: final outputs. Row 0's wave combines the 64 partials; every other
// wave does the 2-way softmax between (s[0], s[row]). Safe in-place: each
// wave reads only its own row + h0copy (staged), then writes its own row.
// grid 2048 x 256
// ---------------------------------------------------------------------------
__global__ __launch_bounds__(256) void final_k(
    const float* __restrict__ h_in, float* __restrict__ h_out,
    const float* __restrict__ s, const float* __restrict__ h0copy,
    const float* __restrict__ partials, const float* __restrict__ zpart)
{
    int row  = (blockIdx.x * blockDim.x + threadIdx.x) >> 6;
    int lane = threadIdx.x & 63;

    if (row == 0) {
        float a = 0.f, z = 0.f;
        #pragma unroll
        for (int b = 0; b < 64; ++b) a += partials[b * DD + lane];
        #pragma unroll
        for (int b = 0; b < 64; ++b) z += zpart[b];
        h_out[lane] = a / z;
    } else {
        float s0 = s[0], si = s[row];
        float m2 = fmaxf(s0, si);
        float p0 = expf(s0 - m2), pi = expf(si - m2);
        float inv = 1.f / (p0 + pi);
        float hv = h_in[row * DD + lane];
        h_out[row * DD + lane] = (p0 * inv) * h0copy[lane] + (pi * inv) * hv;
    }
}

extern "C" void kernel_launch(void* const* d_in, const int* in_sizes, int n_in,
                              void* d_out, int out_size, void* d_ws, size_t ws_size,
                              hipStream_t stream)
{
    const float* x  = (const float*)d_in[0];
    const float* A1 = (const float*)d_in[1];
    const float* A2 = (const float*)d_in[2];
    float* out = (float*)d_out;
    float* ws  = (float*)d_ws;

    // workspace layout (floats): ~58 KB total
    float* s        = ws;               // 8192
    float* pmax     = ws + 8192;        // 2048
    float* h0copy   = ws + 10240;       // 64
    float* partials = ws + 10304;       // 64*64
    float* zpart    = ws + 14400;       // 64

    // layer 1: x -> out
    score_k       <<<2048, 256, 0, stream>>>(x, A1, s, pmax, h0copy);
    row0_partial_k<<<  64, 256, 0, stream>>>(x, s, pmax, partials, zpart);
    final_k       <<<2048, 256, 0, stream>>>(x, out, s, h0copy, partials, zpart);

    // layer 2: out -> out (in place; row 0 staged in h0copy)
    score_k       <<<2048, 256, 0, stream>>>(out, A2, s, pmax, h0copy);
    row0_partial_k<<<  64, 256, 0, stream>>>(out, s, pmax, partials, zpart);
    final_k       <<<2048, 256, 0, stream>>>(out, out, s, h0copy, partials, zpart);
}